// Round 4
// baseline (1911.860 us; speedup 1.0000x reference)
//
#include <hip/hip_runtime.h>
#include <math.h>

#define Bb 16
#define Tt 1024
#define Ss 4096
#define Dd 1024

// lo-part scale: keeps f16 lo-splits in normal range (kills denormal-flush risk)
#define LOSC 2048.0f
#define LOSC_INV (1.0f / 2048.0f)

typedef _Float16 half8 __attribute__((ext_vector_type(8)));
typedef _Float16 half4 __attribute__((ext_vector_type(4)));
typedef float f32x4 __attribute__((ext_vector_type(4)));

__device__ __forceinline__ void gload_lds16(const void* g, void* l) {
    __builtin_amdgcn_global_load_lds((const __attribute__((address_space(1))) void*)g,
                                     (__attribute__((address_space(3))) void*)l, 16, 0, 0);
}

// ---------------------------------------------------------------------------
// split fp32 -> (f16 hi, f16 lo*2^11), elementwise, 8 elems/thread
// ---------------------------------------------------------------------------
__global__ __launch_bounds__(256) void split2(const float* __restrict__ src,
                                              _Float16* __restrict__ d0,
                                              _Float16* __restrict__ d1, size_t n8) {
    size_t i = (size_t)blockIdx.x * 256 + threadIdx.x;
    if (i >= n8) return;
    const float4 v0 = *(const float4*)&src[i * 8];
    const float4 v1 = *(const float4*)&src[i * 8 + 4];
    float x[8] = {v0.x, v0.y, v0.z, v0.w, v1.x, v1.y, v1.z, v1.w};
    half8 h0, h1;
#pragma unroll
    for (int j = 0; j < 8; ++j) {
        _Float16 a = (_Float16)x[j];
        h0[j] = a;
        h1[j] = (_Float16)((x[j] - (float)a) * LOSC);
    }
    *(half8*)&d0[i * 8] = h0;
    *(half8*)&d1[i * 8] = h1;
}

// ---------------------------------------------------------------------------
// transpose + split: src [z][R][C] f32 -> d0/d1 [z][C][R] f16 (lo scaled)
// ---------------------------------------------------------------------------
__global__ __launch_bounds__(256) void splitT(const float* __restrict__ src,
                                              _Float16* __restrict__ d0,
                                              _Float16* __restrict__ d1, int R, int C) {
    __shared__ float t[32][33];
    const size_t zoff = (size_t)blockIdx.z * R * C;
    src += zoff; d0 += zoff; d1 += zoff;
    const int r0 = blockIdx.y * 32, c0 = blockIdx.x * 32;
    const int tr = threadIdx.x >> 3, tc = (threadIdx.x & 7) * 4;
    float4 v = *(const float4*)&src[(size_t)(r0 + tr) * C + c0 + tc];
    t[tr][tc + 0] = v.x; t[tr][tc + 1] = v.y; t[tr][tc + 2] = v.z; t[tr][tc + 3] = v.w;
    __syncthreads();
    half4 h0, h1;
#pragma unroll
    for (int j = 0; j < 4; ++j) {
        float x = t[tc + j][tr];
        _Float16 a = (_Float16)x;
        h0[j] = a;
        h1[j] = (_Float16)((x - (float)a) * LOSC);
    }
    *(half4*)&d0[(size_t)(c0 + tr) * R + r0 + tc] = h0;
    *(half4*)&d1[(size_t)(c0 + tr) * R + r0 + tc] = h1;
}

// ---------------------------------------------------------------------------
// split-f16 MFMA GEMM: C[128x128 tile] = (A0+A1/2^11) . (B0+B1/2^11)^T
// acc_main += a0*b0 ; acc_lo += a0*b1s + a1s*b0 ; C = main + lo*2^-11
// LDS tiles 128row x 32half (64B rows); 16B-chunk XOR swizzle:
//   slot(row, cs) holds global chunk cs ^ ((row>>1)&3)  -> conflict-free b128
//   (write-key == read-key per row since i*16 rows are 0 mod 4 in (row>>1)&3).
// EPI: 0 = write q split (f16 hi / lo*2^11, row len Dd)
//      1 = mask + clamp, write fp32 scores (row len Ss)
//      2 = write fp32 ctx (row len Dd)
// ---------------------------------------------------------------------------
template <int KTOT, int EPI>
__global__ __launch_bounds__(256, 2) void gemm_sp(
    const _Float16* __restrict__ A0, const _Float16* __restrict__ A1,
    const _Float16* __restrict__ B0, const _Float16* __restrict__ B1,
    float* __restrict__ Cf, _Float16* __restrict__ C0, _Float16* __restrict__ C1,
    const int* __restrict__ Ms, size_t sA, size_t sB, size_t sC) {
    __shared__ _Float16 lds[4][128 * 32];  // A0,A1,B0,B1 tiles: 4 x 8KB
    const int z = blockIdx.z;
    A0 += (size_t)z * sA; A1 += (size_t)z * sA;
    B0 += (size_t)z * sB; B1 += (size_t)z * sB;

    const int tid = threadIdx.x;
    const int lane = tid & 63, wave = tid >> 6;
    const int wm = wave >> 1, wn = wave & 1;
    const int m0 = blockIdx.y * 128, n0 = blockIdx.x * 128;
    const int rlo = lane & 15, g = lane >> 4;
    const int sw = (rlo >> 1) & 3;  // read-side swizzle key (row-local)

    const _Float16* Gw = (wave == 0) ? A0 + (size_t)m0 * KTOT
                       : (wave == 1) ? A1 + (size_t)m0 * KTOT
                       : (wave == 2) ? B0 + (size_t)n0 * KTOT
                                     : B1 + (size_t)n0 * KTOT;
    _Float16* Lw = lds[wave];
    // staging: lane l -> tile row i*16 + (l>>2); LDS dest is LINEAR (l*16B);
    // source chunk pre-swizzled so slot(row,cs) = global chunk cs^((row>>1)&3)
    const int srow = lane >> 2;
    const int sgl = (lane & 3) ^ ((srow >> 1) & 3);

    f32x4 acc[4][4] = {};
    f32x4 accL[4][4] = {};
#pragma unroll 1
    for (int k0 = 0; k0 < KTOT; k0 += 32) {
#pragma unroll
        for (int i = 0; i < 8; ++i) {  // 8 wave-issues x 1KB = 8KB tile
            const _Float16* s = Gw + (size_t)(i * 16 + srow) * KTOT + k0 + sgl * 8;
            gload_lds16(s, Lw + i * 512);
        }
        __syncthreads();  // drains vmcnt: staged tiles visible
        half8 a0[4], a1[4], b0f[4], b1f[4];
#pragma unroll
        for (int x = 0; x < 4; ++x) {
            const int ra = (wm * 64 + x * 16 + rlo) * 32 + ((g ^ sw) * 8);
            a0[x]  = *(const half8*)&lds[0][ra];
            a1[x]  = *(const half8*)&lds[1][ra];
            const int rb = (wn * 64 + x * 16 + rlo) * 32 + ((g ^ sw) * 8);
            b0f[x] = *(const half8*)&lds[2][rb];
            b1f[x] = *(const half8*)&lds[3][rb];
        }
#pragma unroll
        for (int mt = 0; mt < 4; ++mt)
#pragma unroll
            for (int nt = 0; nt < 4; ++nt) {
                acc[mt][nt]  = __builtin_amdgcn_mfma_f32_16x16x32_f16(a0[mt], b0f[nt], acc[mt][nt], 0, 0, 0);
                accL[mt][nt] = __builtin_amdgcn_mfma_f32_16x16x32_f16(a0[mt], b1f[nt], accL[mt][nt], 0, 0, 0);
                accL[mt][nt] = __builtin_amdgcn_mfma_f32_16x16x32_f16(a1[mt], b0f[nt], accL[mt][nt], 0, 0, 0);
            }
        __syncthreads();  // compute done before next stage overwrites
    }

    // epilogue. C/D layout: col = lane&15, row = (lane>>4)*4 + i  [HW-verified]
    float* Cz = Cf ? Cf + (size_t)z * sC : nullptr;
#pragma unroll
    for (int nt = 0; nt < 4; ++nt) {
        const int c = n0 + wn * 64 + nt * 16 + rlo;
        int mk = 0;
        if (EPI == 1) mk = Ms[(size_t)z * Ss + c];
#pragma unroll
        for (int mt = 0; mt < 4; ++mt) {
            const int r0 = m0 + wm * 64 + mt * 16 + g * 4;
#pragma unroll
            for (int i = 0; i < 4; ++i) {
                float v = acc[mt][nt][i] + accL[mt][nt][i] * LOSC_INV;
                if (EPI == 0) {
                    _Float16 h0 = (_Float16)v;
                    C0[(size_t)(r0 + i) * Dd + c] = h0;
                    C1[(size_t)(r0 + i) * Dd + c] = (_Float16)((v - (float)h0) * LOSC);
                } else if (EPI == 1) {
                    Cz[(size_t)(r0 + i) * Ss + c] = mk ? fmaxf(v, -1e10f) : -1e10f;
                } else {
                    Cz[(size_t)(r0 + i) * Dd + c] = v;
                }
            }
        }
    }
}

// ---------------------------------------------------------------------------
// row softmax (S=4096, block=256) + optional f16 hi/lo*2^11 split of P
// ---------------------------------------------------------------------------
__global__ __launch_bounds__(256) void softmax_sp(float* __restrict__ Sc,
                                                  _Float16* __restrict__ P0,
                                                  _Float16* __restrict__ P1, int do_split) {
    float* p = Sc + (size_t)blockIdx.x * Ss;
    const int t = threadIdx.x;
    const int wv = t >> 6, ln = t & 63;
    __shared__ float red[8];
    float4 v[4];
    float mx = -3.4e38f;
#pragma unroll
    for (int i = 0; i < 4; ++i) {
        v[i] = *(float4*)&p[i * 1024 + t * 4];
        mx = fmaxf(mx, fmaxf(fmaxf(v[i].x, v[i].y), fmaxf(v[i].z, v[i].w)));
    }
#pragma unroll
    for (int o = 32; o; o >>= 1) mx = fmaxf(mx, __shfl_xor(mx, o));
    if (!ln) red[wv] = mx;
    __syncthreads();
    mx = fmaxf(fmaxf(red[0], red[1]), fmaxf(red[2], red[3]));
    float sm = 0.f;
#pragma unroll
    for (int i = 0; i < 4; ++i) {
        v[i].x = expf(v[i].x - mx); v[i].y = expf(v[i].y - mx);
        v[i].z = expf(v[i].z - mx); v[i].w = expf(v[i].w - mx);
        sm += (v[i].x + v[i].y) + (v[i].z + v[i].w);
    }
#pragma unroll
    for (int o = 32; o; o >>= 1) sm += __shfl_xor(sm, o);
    if (!ln) red[4 + wv] = sm;
    __syncthreads();
    sm = (red[4] + red[5]) + (red[6] + red[7]);
    const float inv = 1.0f / sm;
#pragma unroll
    for (int i = 0; i < 4; ++i) {
        v[i].x *= inv; v[i].y *= inv; v[i].z *= inv; v[i].w *= inv;
        *(float4*)&p[i * 1024 + t * 4] = v[i];
        if (do_split) {
            float xs[4] = {v[i].x, v[i].y, v[i].z, v[i].w};
            half4 h0, h1;
#pragma unroll
            for (int j = 0; j < 4; ++j) {
                _Float16 a = (_Float16)xs[j];
                h0[j] = a;
                h1[j] = (_Float16)((xs[j] - (float)a) * LOSC);
            }
            *(half4*)&P0[(size_t)blockIdx.x * Ss + i * 1024 + t * 4] = h0;
            *(half4*)&P1[(size_t)blockIdx.x * Ss + i * 1024 + t * 4] = h1;
        }
    }
}

// ===========================================================================
// fp32-vector fallback (used only if ws_size can't hold the f16 split arrays)
// ===========================================================================
#define TILE 128
#define KST 8
__global__ __launch_bounds__(256) void fb_gemm_q(const float* __restrict__ A,
                                                 const float* __restrict__ Bm,
                                                 float* __restrict__ C) {
    __shared__ float As[KST][TILE];
    __shared__ float Bs[KST][TILE];
    const int tid = threadIdx.x, tx = tid & 15, ty = tid >> 4;
    const int m0 = blockIdx.y * TILE, n0 = blockIdx.x * TILE;
    const int ar = tid >> 1, ac = (tid & 1) * 4;
    const int br = tid >> 5, bc = (tid & 31) * 4;
    float acc[8][8] = {};
    for (int k0 = 0; k0 < Dd; k0 += KST) {
        float4 av = *(const float4*)&A[(size_t)(m0 + ar) * Dd + k0 + ac];
        float4 bv = *(const float4*)&Bm[(size_t)(k0 + br) * Dd + n0 + bc];
        __syncthreads();
        As[ac + 0][ar] = av.x; As[ac + 1][ar] = av.y;
        As[ac + 2][ar] = av.z; As[ac + 3][ar] = av.w;
        *(float4*)&Bs[br][bc] = bv;
        __syncthreads();
#pragma unroll
        for (int k = 0; k < KST; ++k) {
            float a[8], b[8];
            *(float4*)(a) = *(float4*)&As[k][ty * 8];
            *(float4*)(a + 4) = *(float4*)&As[k][ty * 8 + 4];
            *(float4*)(b) = *(float4*)&Bs[k][tx * 8];
            *(float4*)(b + 4) = *(float4*)&Bs[k][tx * 8 + 4];
#pragma unroll
            for (int i = 0; i < 8; ++i)
#pragma unroll
                for (int j = 0; j < 8; ++j) acc[i][j] = fmaf(a[i], b[j], acc[i][j]);
        }
    }
#pragma unroll
    for (int i = 0; i < 8; ++i) {
        float* cp = &C[(size_t)(m0 + ty * 8 + i) * Dd + n0 + tx * 8];
        *(float4*)(cp) = *(float4*)&acc[i][0];
        *(float4*)(cp + 4) = *(float4*)&acc[i][4];
    }
}

__global__ __launch_bounds__(256) void fb_gemm_scores(const float* __restrict__ Q,
                                                      const float* __restrict__ Hs,
                                                      const int* __restrict__ Msk,
                                                      float* __restrict__ Sc) {
    const int b = blockIdx.z;
    const float* A = Q + (size_t)b * Tt * Dd;
    const float* Bt = Hs + (size_t)b * Ss * Dd;
    float* C = Sc + (size_t)b * Tt * Ss;
    __shared__ float As[KST][TILE];
    __shared__ float Bs[KST][TILE];
    __shared__ int msk[TILE];
    const int tid = threadIdx.x, tx = tid & 15, ty = tid >> 4;
    const int m0 = blockIdx.y * TILE, n0 = blockIdx.x * TILE;
    if (tid < TILE) msk[tid] = Msk[b * Ss + n0 + tid];
    const int r = tid >> 1, c = (tid & 1) * 4;
    float acc[8][8] = {};
    for (int k0 = 0; k0 < Dd; k0 += KST) {
        float4 av = *(const float4*)&A[(size_t)(m0 + r) * Dd + k0 + c];
        float4 bv = *(const float4*)&Bt[(size_t)(n0 + r) * Dd + k0 + c];
        __syncthreads();
        As[c + 0][r] = av.x; As[c + 1][r] = av.y;
        As[c + 2][r] = av.z; As[c + 3][r] = av.w;
        Bs[c + 0][r] = bv.x; Bs[c + 1][r] = bv.y;
        Bs[c + 2][r] = bv.z; Bs[c + 3][r] = bv.w;
        __syncthreads();
#pragma unroll
        for (int k = 0; k < KST; ++k) {
            float a[8], b2[8];
            *(float4*)(a) = *(float4*)&As[k][ty * 8];
            *(float4*)(a + 4) = *(float4*)&As[k][ty * 8 + 4];
            *(float4*)(b2) = *(float4*)&Bs[k][tx * 8];
            *(float4*)(b2 + 4) = *(float4*)&Bs[k][tx * 8 + 4];
#pragma unroll
            for (int i = 0; i < 8; ++i)
#pragma unroll
                for (int j = 0; j < 8; ++j) acc[i][j] = fmaf(a[i], b2[j], acc[i][j]);
        }
    }
#pragma unroll
    for (int i = 0; i < 8; ++i) {
        float out[8];
#pragma unroll
        for (int j = 0; j < 8; ++j)
            out[j] = msk[tx * 8 + j] ? fmaxf(acc[i][j], -1e10f) : -1e10f;
        float* cp = &C[(size_t)(m0 + ty * 8 + i) * Ss + n0 + tx * 8];
        *(float4*)(cp) = *(float4*)&out[0];
        *(float4*)(cp + 4) = *(float4*)&out[4];
    }
}

__global__ __launch_bounds__(256) void fb_gemm_ctx(const float* __restrict__ Sc,
                                                   const float* __restrict__ Hs,
                                                   float* __restrict__ Ctx) {
    const int b = blockIdx.z;
    const float* A = Sc + (size_t)b * Tt * Ss;
    const float* Bm = Hs + (size_t)b * Ss * Dd;
    float* C = Ctx + (size_t)b * Tt * Dd;
    __shared__ float As[KST][TILE];
    __shared__ float Bs[KST][TILE];
    const int tid = threadIdx.x, tx = tid & 15, ty = tid >> 4;
    const int m0 = blockIdx.y * TILE, n0 = blockIdx.x * TILE;
    const int ar = tid >> 1, ac = (tid & 1) * 4;
    const int br = tid >> 5, bc = (tid & 31) * 4;
    float acc[8][8] = {};
    for (int k0 = 0; k0 < Ss; k0 += KST) {
        float4 av = *(const float4*)&A[(size_t)(m0 + ar) * Ss + k0 + ac];
        float4 bv = *(const float4*)&Bm[(size_t)(k0 + br) * Dd + n0 + bc];
        __syncthreads();
        As[ac + 0][ar] = av.x; As[ac + 1][ar] = av.y;
        As[ac + 2][ar] = av.z; As[ac + 3][ar] = av.w;
        *(float4*)&Bs[br][bc] = bv;
        __syncthreads();
#pragma unroll
        for (int k = 0; k < KST; ++k) {
            float a[8], b2[8];
            *(float4*)(a) = *(float4*)&As[k][ty * 8];
            *(float4*)(a + 4) = *(float4*)&As[k][ty * 8 + 4];
            *(float4*)(b2) = *(float4*)&Bs[k][tx * 8];
            *(float4*)(b2 + 4) = *(float4*)&Bs[k][tx * 8 + 4];
#pragma unroll
            for (int i = 0; i < 8; ++i)
#pragma unroll
                for (int j = 0; j < 8; ++j) acc[i][j] = fmaf(a[i], b2[j], acc[i][j]);
        }
    }
#pragma unroll
    for (int i = 0; i < 8; ++i) {
        float* cp = &C[(size_t)(m0 + ty * 8 + i) * Dd + n0 + tx * 8];
        *(float4*)(cp) = *(float4*)&acc[i][0];
        *(float4*)(cp + 4) = *(float4*)&acc[i][4];
    }
}

// ---------------------------------------------------------------------------
extern "C" void kernel_launch(void* const* d_in, const int* in_sizes, int n_in,
                              void* d_out, int out_size, void* d_ws, size_t ws_size,
                              hipStream_t stream) {
    const float* h_t = (const float*)d_in[0];   // [B,T,D]
    const float* h_s = (const float*)d_in[1];   // [B,S,D]
    const float* W_in = (const float*)d_in[2];  // [D,D]
    const int* m_s = (const int*)d_in[3];       // [B,S]

    float* ctx = (float*)d_out;                            // [B,T,D]
    float* scores = (float*)d_out + (size_t)Bb * Tt * Dd;  // [B,T,S]

    const size_t NHS = (size_t)Bb * Ss * Dd;  // 67,108,864 (== B*T*S = P elems)
    const size_t NHT = (size_t)Bb * Tt * Dd;  // 16,777,216
    const size_t NW = (size_t)Dd * Dd;        // 1,048,576
    // hs0/hs1 are dead after gemm_scores; p0/p1 alias them (same size).
    // need = (hs:2*NHS + hsT:2*NHS + ht:2*NHT + w:2*NW + q:2*NHT) halfs = 675 MB
    const size_t need = (4 * NHS + 4 * NHT + 2 * NW) * sizeof(_Float16);

    if (ws_size >= need) {
        _Float16* w = (_Float16*)d_ws;
        _Float16* hs0 = w;  w += NHS;   // reused as p0 after gemm_scores
        _Float16* hs1 = w;  w += NHS;   // reused as p1 after gemm_scores
        _Float16* hsT0 = w; w += NHS;
        _Float16* hsT1 = w; w += NHS;
        _Float16* ht0 = w;  w += NHT;
        _Float16* ht1 = w;  w += NHT;
        _Float16* wT0 = w;  w += NW;
        _Float16* wT1 = w;  w += NW;
        _Float16* q0 = w;   w += NHT;
        _Float16* q1 = w;   w += NHT;
        _Float16* p0 = hs0;             // overlay: hs split dead before softmax
        _Float16* p1 = hs1;

        split2<<<(unsigned)(NHT / 8 / 256), 256, 0, stream>>>(h_t, ht0, ht1, NHT / 8);
        split2<<<(unsigned)(NHS / 8 / 256), 256, 0, stream>>>(h_s, hs0, hs1, NHS / 8);
        splitT<<<dim3(Dd / 32, Dd / 32, 1), 256, 0, stream>>>(W_in, wT0, wT1, Dd, Dd);
        splitT<<<dim3(Dd / 32, Ss / 32, Bb), 256, 0, stream>>>(h_s, hsT0, hsT1, Ss, Dd);

        // q = h_t @ W_in  (B-operand = W^T pre-transposed, both [row][k]) -> f16 split
        gemm_sp<Dd, 0><<<dim3(Dd / 128, (Bb * Tt) / 128, 1), 256, 0, stream>>>(
            ht0, ht1, wT0, wT1, nullptr, q0, q1, nullptr, 0, 0, 0);
        // scores = q @ h_s^T + mask/clamp   (last reader of hs0/hs1)
        gemm_sp<Dd, 1><<<dim3(Ss / 128, Tt / 128, Bb), 256, 0, stream>>>(
            q0, q1, hs0, hs1, scores, nullptr, nullptr, m_s,
            (size_t)Tt * Dd, (size_t)Ss * Dd, (size_t)Tt * Ss);
        // softmax + P split (writes p0/p1 over the dead hs split; stream-ordered)
        softmax_sp<<<Bb * Tt, 256, 0, stream>>>(scores, p0, p1, 1);
        // ctx = P @ h_s  (B-operand = h_s^T pre-transposed)
        gemm_sp<Ss, 2><<<dim3(Dd / 128, Tt / 128, Bb), 256, 0, stream>>>(
            p0, p1, hsT0, hsT1, ctx, nullptr, nullptr, nullptr,
            (size_t)Tt * Ss, (size_t)Dd * Ss, (size_t)Tt * Dd);
    } else {
        // fp32-vector fallback: only needs q scratch (67 MB)
        float* q = (float*)d_ws;
        fb_gemm_q<<<dim3(Dd / TILE, (Bb * Tt) / TILE), 256, 0, stream>>>(h_t, W_in, q);
        fb_gemm_scores<<<dim3(Ss / TILE, Tt / TILE, Bb), 256, 0, stream>>>(q, h_s, m_s, scores);
        softmax_sp<<<Bb * Tt, 256, 0, stream>>>(scores, nullptr, nullptr, 0);
        fb_gemm_ctx<<<dim3(Dd / TILE, Tt / TILE, Bb), 256, 0, stream>>>(scores, h_s, ctx);
    }
}

// Round 5
// 1585.353 us; speedup vs baseline: 1.2060x; 1.2060x over previous
//
#include <hip/hip_runtime.h>
#include <math.h>

#define Bb 16
#define Tt 1024
#define Ss 4096
#define Dd 1024

// lo-part scale: keeps f16 lo-splits in normal range (kills denormal-flush risk)
#define LOSC 2048.0f
#define LOSC_INV (1.0f / 2048.0f)

typedef _Float16 half8 __attribute__((ext_vector_type(8)));
typedef _Float16 half4 __attribute__((ext_vector_type(4)));
typedef float f32x4 __attribute__((ext_vector_type(4)));

__device__ __forceinline__ void gload_lds16(const void* g, void* l) {
    __builtin_amdgcn_global_load_lds((const __attribute__((address_space(1))) void*)g,
                                     (__attribute__((address_space(3))) void*)l, 16, 0, 0);
}

// ---------------------------------------------------------------------------
// split fp32 -> (f16 hi, f16 lo*2^11), elementwise, 8 elems/thread
// ---------------------------------------------------------------------------
__global__ __launch_bounds__(256) void split2(const float* __restrict__ src,
                                              _Float16* __restrict__ d0,
                                              _Float16* __restrict__ d1, size_t n8) {
    size_t i = (size_t)blockIdx.x * 256 + threadIdx.x;
    if (i >= n8) return;
    const float4 v0 = *(const float4*)&src[i * 8];
    const float4 v1 = *(const float4*)&src[i * 8 + 4];
    float x[8] = {v0.x, v0.y, v0.z, v0.w, v1.x, v1.y, v1.z, v1.w};
    half8 h0, h1;
#pragma unroll
    for (int j = 0; j < 8; ++j) {
        _Float16 a = (_Float16)x[j];
        h0[j] = a;
        h1[j] = (_Float16)((x[j] - (float)a) * LOSC);
    }
    *(half8*)&d0[i * 8] = h0;
    *(half8*)&d1[i * 8] = h1;
}

// ---------------------------------------------------------------------------
// transpose + split: src [z][R][C] f32 -> d0/d1 [z][C][R] f16 (lo scaled)
// ---------------------------------------------------------------------------
__global__ __launch_bounds__(256) void splitT(const float* __restrict__ src,
                                              _Float16* __restrict__ d0,
                                              _Float16* __restrict__ d1, int R, int C) {
    __shared__ float t[32][33];
    const size_t zoff = (size_t)blockIdx.z * R * C;
    src += zoff; d0 += zoff; d1 += zoff;
    const int r0 = blockIdx.y * 32, c0 = blockIdx.x * 32;
    const int tr = threadIdx.x >> 3, tc = (threadIdx.x & 7) * 4;
    float4 v = *(const float4*)&src[(size_t)(r0 + tr) * C + c0 + tc];
    t[tr][tc + 0] = v.x; t[tr][tc + 1] = v.y; t[tr][tc + 2] = v.z; t[tr][tc + 3] = v.w;
    __syncthreads();
    half4 h0, h1;
#pragma unroll
    for (int j = 0; j < 4; ++j) {
        float x = t[tc + j][tr];
        _Float16 a = (_Float16)x;
        h0[j] = a;
        h1[j] = (_Float16)((x - (float)a) * LOSC);
    }
    *(half4*)&d0[(size_t)(c0 + tr) * R + r0 + tc] = h0;
    *(half4*)&d1[(size_t)(c0 + tr) * R + r0 + tc] = h1;
}

// transpose, hi-part only: src [z][R][C] f32 -> d0 [z][C][R] f16
__global__ __launch_bounds__(256) void splitT_hi(const float* __restrict__ src,
                                                 _Float16* __restrict__ d0, int R, int C) {
    __shared__ float t[32][33];
    const size_t zoff = (size_t)blockIdx.z * R * C;
    src += zoff; d0 += zoff;
    const int r0 = blockIdx.y * 32, c0 = blockIdx.x * 32;
    const int tr = threadIdx.x >> 3, tc = (threadIdx.x & 7) * 4;
    float4 v = *(const float4*)&src[(size_t)(r0 + tr) * C + c0 + tc];
    t[tr][tc + 0] = v.x; t[tr][tc + 1] = v.y; t[tr][tc + 2] = v.z; t[tr][tc + 3] = v.w;
    __syncthreads();
    half4 h0;
#pragma unroll
    for (int j = 0; j < 4; ++j) h0[j] = (_Float16)t[tc + j][tr];
    *(half4*)&d0[(size_t)(c0 + tr) * R + r0 + tc] = h0;
}

// ---------------------------------------------------------------------------
// split-f16 MFMA GEMM: C[128x128 tile] = (A0+A1/2^11) . (B0+B1/2^11)^T
// acc_main += a0*b0 ; acc_lo += a0*b1s + a1s*b0 ; C = main + lo*2^-11
// LDS tiles 128row x 32half (64B rows); 16B-chunk XOR swizzle:
//   slot(row, cs) holds global chunk cs ^ ((row>>1)&3)  -> conflict-free b128
//   (write-key == read-key per row since i*16 rows are 0 mod 4 in (row>>1)&3).
// EPI: 0 = write q split (f16 hi / lo*2^11, row len Dd)
//      1 = mask + clamp, write fp32 scores (row len Ss)
// ---------------------------------------------------------------------------
template <int KTOT, int EPI>
__global__ __launch_bounds__(256, 2) void gemm_sp(
    const _Float16* __restrict__ A0, const _Float16* __restrict__ A1,
    const _Float16* __restrict__ B0, const _Float16* __restrict__ B1,
    float* __restrict__ Cf, _Float16* __restrict__ C0, _Float16* __restrict__ C1,
    const int* __restrict__ Ms, size_t sA, size_t sB, size_t sC) {
    __shared__ _Float16 lds[4][128 * 32];  // A0,A1,B0,B1 tiles: 4 x 8KB
    const int z = blockIdx.z;
    A0 += (size_t)z * sA; A1 += (size_t)z * sA;
    B0 += (size_t)z * sB; B1 += (size_t)z * sB;

    const int tid = threadIdx.x;
    const int lane = tid & 63, wave = tid >> 6;
    const int wm = wave >> 1, wn = wave & 1;
    const int m0 = blockIdx.y * 128, n0 = blockIdx.x * 128;
    const int rlo = lane & 15, g = lane >> 4;
    const int sw = (rlo >> 1) & 3;  // read-side swizzle key (row-local)

    const _Float16* Gw = (wave == 0) ? A0 + (size_t)m0 * KTOT
                       : (wave == 1) ? A1 + (size_t)m0 * KTOT
                       : (wave == 2) ? B0 + (size_t)n0 * KTOT
                                     : B1 + (size_t)n0 * KTOT;
    _Float16* Lw = lds[wave];
    // staging: lane l -> tile row i*16 + (l>>2); LDS dest is LINEAR (l*16B);
    // source chunk pre-swizzled so slot(row,cs) = global chunk cs^((row>>1)&3)
    const int srow = lane >> 2;
    const int sgl = (lane & 3) ^ ((srow >> 1) & 3);

    f32x4 acc[4][4] = {};
    f32x4 accL[4][4] = {};
#pragma unroll 1
    for (int k0 = 0; k0 < KTOT; k0 += 32) {
#pragma unroll
        for (int i = 0; i < 8; ++i) {  // 8 wave-issues x 1KB = 8KB tile
            const _Float16* s = Gw + (size_t)(i * 16 + srow) * KTOT + k0 + sgl * 8;
            gload_lds16(s, Lw + i * 512);
        }
        __syncthreads();  // drains vmcnt: staged tiles visible
        half8 a0[4], a1[4], b0f[4], b1f[4];
#pragma unroll
        for (int x = 0; x < 4; ++x) {
            const int ra = (wm * 64 + x * 16 + rlo) * 32 + ((g ^ sw) * 8);
            a0[x]  = *(const half8*)&lds[0][ra];
            a1[x]  = *(const half8*)&lds[1][ra];
            const int rb = (wn * 64 + x * 16 + rlo) * 32 + ((g ^ sw) * 8);
            b0f[x] = *(const half8*)&lds[2][rb];
            b1f[x] = *(const half8*)&lds[3][rb];
        }
#pragma unroll
        for (int mt = 0; mt < 4; ++mt)
#pragma unroll
            for (int nt = 0; nt < 4; ++nt) {
                acc[mt][nt]  = __builtin_amdgcn_mfma_f32_16x16x32_f16(a0[mt], b0f[nt], acc[mt][nt], 0, 0, 0);
                accL[mt][nt] = __builtin_amdgcn_mfma_f32_16x16x32_f16(a0[mt], b1f[nt], accL[mt][nt], 0, 0, 0);
                accL[mt][nt] = __builtin_amdgcn_mfma_f32_16x16x32_f16(a1[mt], b0f[nt], accL[mt][nt], 0, 0, 0);
            }
        __syncthreads();  // compute done before next stage overwrites
    }

    // epilogue. C/D layout: col = lane&15, row = (lane>>4)*4 + i  [HW-verified]
    float* Cz = Cf ? Cf + (size_t)z * sC : nullptr;
#pragma unroll
    for (int nt = 0; nt < 4; ++nt) {
        const int c = n0 + wn * 64 + nt * 16 + rlo;
        int mk = 0;
        if (EPI == 1) mk = Ms[(size_t)z * Ss + c];
#pragma unroll
        for (int mt = 0; mt < 4; ++mt) {
            const int r0 = m0 + wm * 64 + mt * 16 + g * 4;
#pragma unroll
            for (int i = 0; i < 4; ++i) {
                float v = acc[mt][nt][i] + accL[mt][nt][i] * LOSC_INV;
                if (EPI == 0) {
                    _Float16 h0 = (_Float16)v;
                    C0[(size_t)(r0 + i) * Dd + c] = h0;
                    C1[(size_t)(r0 + i) * Dd + c] = (_Float16)((v - (float)h0) * LOSC);
                } else {
                    Cz[(size_t)(r0 + i) * Ss + c] = mk ? fmaxf(v, -1e10f) : -1e10f;
                }
            }
        }
    }
}

// ---------------------------------------------------------------------------
// hi-only MFMA GEMM for ctx = P(hi) @ h_s(hi):  1 MFMA per k-chunk pair.
// A0 [M rows][4096], B0 [N rows][4096] (hsT, d-major), C fp32 [M][Dd].
// Error <= sum_s p*|h|*2^-10 ~ 1e-3 — below accepted absmax (0.0156, scores).
// Same swizzle scheme; 2 LDS tiles, waves 0/1 stage A halves, 2/3 B halves.
// ---------------------------------------------------------------------------
__global__ __launch_bounds__(256, 2) void gemm_hi(
    const _Float16* __restrict__ A0, const _Float16* __restrict__ B0,
    float* __restrict__ Cf, size_t sA, size_t sB, size_t sC) {
    __shared__ _Float16 lds[2][128 * 32];  // A,B tiles: 2 x 8KB
    const int z = blockIdx.z;
    A0 += (size_t)z * sA; B0 += (size_t)z * sB;

    const int tid = threadIdx.x;
    const int lane = tid & 63, wave = tid >> 6;
    const int wm = wave >> 1, wn = wave & 1;
    const int m0 = blockIdx.y * 128, n0 = blockIdx.x * 128;
    const int rlo = lane & 15, g = lane >> 4;
    const int sw = (rlo >> 1) & 3;

    const _Float16* Gw = (wave < 2) ? A0 + (size_t)m0 * 4096 : B0 + (size_t)n0 * 4096;
    _Float16* Lw = lds[wave >> 1] + (wave & 1) * (64 * 32);  // half-tile per wave
    const int srow = lane >> 2;
    const int sgl = (lane & 3) ^ ((srow >> 1) & 3);
    const int rbase = (wave & 1) * 64;  // 64 ≡ 0 mod 4 in (row>>1)&3: key preserved

    f32x4 acc[4][4] = {};
#pragma unroll 1
    for (int k0 = 0; k0 < 4096; k0 += 32) {
#pragma unroll
        for (int i = 0; i < 4; ++i) {  // 4 wave-issues x 1KB = half-tile
            const _Float16* s = Gw + (size_t)(rbase + i * 16 + srow) * 4096 + k0 + sgl * 8;
            gload_lds16(s, Lw + i * 512);
        }
        __syncthreads();
        half8 af[4], bf[4];
#pragma unroll
        for (int x = 0; x < 4; ++x) {
            const int ra = (wm * 64 + x * 16 + rlo) * 32 + ((g ^ sw) * 8);
            af[x] = *(const half8*)&lds[0][ra];
            const int rb = (wn * 64 + x * 16 + rlo) * 32 + ((g ^ sw) * 8);
            bf[x] = *(const half8*)&lds[1][rb];
        }
#pragma unroll
        for (int mt = 0; mt < 4; ++mt)
#pragma unroll
            for (int nt = 0; nt < 4; ++nt)
                acc[mt][nt] = __builtin_amdgcn_mfma_f32_16x16x32_f16(af[mt], bf[nt], acc[mt][nt], 0, 0, 0);
        __syncthreads();
    }

    float* Cz = Cf + (size_t)z * sC;
#pragma unroll
    for (int nt = 0; nt < 4; ++nt) {
        const int c = n0 + wn * 64 + nt * 16 + rlo;
#pragma unroll
        for (int mt = 0; mt < 4; ++mt) {
            const int r0 = m0 + wm * 64 + mt * 16 + g * 4;
#pragma unroll
            for (int i = 0; i < 4; ++i)
                Cz[(size_t)(r0 + i) * Dd + c] = acc[mt][nt][i];
        }
    }
}

// ---------------------------------------------------------------------------
// row softmax (S=4096, block=256) + optional f16-hi write of P
// ---------------------------------------------------------------------------
__global__ __launch_bounds__(256) void softmax_sp(float* __restrict__ Sc,
                                                  _Float16* __restrict__ P0, int do_split) {
    float* p = Sc + (size_t)blockIdx.x * Ss;
    const int t = threadIdx.x;
    const int wv = t >> 6, ln = t & 63;
    __shared__ float red[8];
    float4 v[4];
    float mx = -3.4e38f;
#pragma unroll
    for (int i = 0; i < 4; ++i) {
        v[i] = *(float4*)&p[i * 1024 + t * 4];
        mx = fmaxf(mx, fmaxf(fmaxf(v[i].x, v[i].y), fmaxf(v[i].z, v[i].w)));
    }
#pragma unroll
    for (int o = 32; o; o >>= 1) mx = fmaxf(mx, __shfl_xor(mx, o));
    if (!ln) red[wv] = mx;
    __syncthreads();
    mx = fmaxf(fmaxf(red[0], red[1]), fmaxf(red[2], red[3]));
    float sm = 0.f;
#pragma unroll
    for (int i = 0; i < 4; ++i) {
        v[i].x = expf(v[i].x - mx); v[i].y = expf(v[i].y - mx);
        v[i].z = expf(v[i].z - mx); v[i].w = expf(v[i].w - mx);
        sm += (v[i].x + v[i].y) + (v[i].z + v[i].w);
    }
#pragma unroll
    for (int o = 32; o; o >>= 1) sm += __shfl_xor(sm, o);
    if (!ln) red[4 + wv] = sm;
    __syncthreads();
    sm = (red[4] + red[5]) + (red[6] + red[7]);
    const float inv = 1.0f / sm;
#pragma unroll
    for (int i = 0; i < 4; ++i) {
        v[i].x *= inv; v[i].y *= inv; v[i].z *= inv; v[i].w *= inv;
        *(float4*)&p[i * 1024 + t * 4] = v[i];
        if (do_split) {
            half4 h0 = {(_Float16)v[i].x, (_Float16)v[i].y, (_Float16)v[i].z, (_Float16)v[i].w};
            *(half4*)&P0[(size_t)blockIdx.x * Ss + i * 1024 + t * 4] = h0;
        }
    }
}

// ===========================================================================
// fp32-vector fallback (used only if ws_size can't hold the f16 split arrays)
// ===========================================================================
#define TILE 128
#define KST 8
__global__ __launch_bounds__(256) void fb_gemm_q(const float* __restrict__ A,
                                                 const float* __restrict__ Bm,
                                                 float* __restrict__ C) {
    __shared__ float As[KST][TILE];
    __shared__ float Bs[KST][TILE];
    const int tid = threadIdx.x, tx = tid & 15, ty = tid >> 4;
    const int m0 = blockIdx.y * TILE, n0 = blockIdx.x * TILE;
    const int ar = tid >> 1, ac = (tid & 1) * 4;
    const int br = tid >> 5, bc = (tid & 31) * 4;
    float acc[8][8] = {};
    for (int k0 = 0; k0 < Dd; k0 += KST) {
        float4 av = *(const float4*)&A[(size_t)(m0 + ar) * Dd + k0 + ac];
        float4 bv = *(const float4*)&Bm[(size_t)(k0 + br) * Dd + n0 + bc];
        __syncthreads();
        As[ac + 0][ar] = av.x; As[ac + 1][ar] = av.y;
        As[ac + 2][ar] = av.z; As[ac + 3][ar] = av.w;
        *(float4*)&Bs[br][bc] = bv;
        __syncthreads();
#pragma unroll
        for (int k = 0; k < KST; ++k) {
            float a[8], b[8];
            *(float4*)(a) = *(float4*)&As[k][ty * 8];
            *(float4*)(a + 4) = *(float4*)&As[k][ty * 8 + 4];
            *(float4*)(b) = *(float4*)&Bs[k][tx * 8];
            *(float4*)(b + 4) = *(float4*)&Bs[k][tx * 8 + 4];
#pragma unroll
            for (int i = 0; i < 8; ++i)
#pragma unroll
                for (int j = 0; j < 8; ++j) acc[i][j] = fmaf(a[i], b[j], acc[i][j]);
        }
    }
#pragma unroll
    for (int i = 0; i < 8; ++i) {
        float* cp = &C[(size_t)(m0 + ty * 8 + i) * Dd + n0 + tx * 8];
        *(float4*)(cp) = *(float4*)&acc[i][0];
        *(float4*)(cp + 4) = *(float4*)&acc[i][4];
    }
}

__global__ __launch_bounds__(256) void fb_gemm_scores(const float* __restrict__ Q,
                                                      const float* __restrict__ Hs,
                                                      const int* __restrict__ Msk,
                                                      float* __restrict__ Sc) {
    const int b = blockIdx.z;
    const float* A = Q + (size_t)b * Tt * Dd;
    const float* Bt = Hs + (size_t)b * Ss * Dd;
    float* C = Sc + (size_t)b * Tt * Ss;
    __shared__ float As[KST][TILE];
    __shared__ float Bs[KST][TILE];
    __shared__ int msk[TILE];
    const int tid = threadIdx.x, tx = tid & 15, ty = tid >> 4;
    const int m0 = blockIdx.y * TILE, n0 = blockIdx.x * TILE;
    if (tid < TILE) msk[tid] = Msk[b * Ss + n0 + tid];
    const int r = tid >> 1, c = (tid & 1) * 4;
    float acc[8][8] = {};
    for (int k0 = 0; k0 < Dd; k0 += KST) {
        float4 av = *(const float4*)&A[(size_t)(m0 + r) * Dd + k0 + c];
        float4 bv = *(const float4*)&Bt[(size_t)(n0 + r) * Dd + k0 + c];
        __syncthreads();
        As[c + 0][r] = av.x; As[c + 1][r] = av.y;
        As[c + 2][r] = av.z; As[c + 3][r] = av.w;
        Bs[c + 0][r] = bv.x; Bs[c + 1][r] = bv.y;
        Bs[c + 2][r] = bv.z; Bs[c + 3][r] = bv.w;
        __syncthreads();
#pragma unroll
        for (int k = 0; k < KST; ++k) {
            float a[8], b2[8];
            *(float4*)(a) = *(float4*)&As[k][ty * 8];
            *(float4*)(a + 4) = *(float4*)&As[k][ty * 8 + 4];
            *(float4*)(b2) = *(float4*)&Bs[k][tx * 8];
            *(float4*)(b2 + 4) = *(float4*)&Bs[k][tx * 8 + 4];
#pragma unroll
            for (int i = 0; i < 8; ++i)
#pragma unroll
                for (int j = 0; j < 8; ++j) acc[i][j] = fmaf(a[i], b2[j], acc[i][j]);
        }
    }
#pragma unroll
    for (int i = 0; i < 8; ++i) {
        float out[8];
#pragma unroll
        for (int j = 0; j < 8; ++j)
            out[j] = msk[tx * 8 + j] ? fmaxf(acc[i][j], -1e10f) : -1e10f;
        float* cp = &C[(size_t)(m0 + ty * 8 + i) * Ss + n0 + tx * 8];
        *(float4*)(cp) = *(float4*)&out[0];
        *(float4*)(cp + 4) = *(float4*)&out[4];
    }
}

__global__ __launch_bounds__(256) void fb_gemm_ctx(const float* __restrict__ Sc,
                                                   const float* __restrict__ Hs,
                                                   float* __restrict__ Ctx) {
    const int b = blockIdx.z;
    const float* A = Sc + (size_t)b * Tt * Ss;
    const float* Bm = Hs + (size_t)b * Ss * Dd;
    float* C = Ctx + (size_t)b * Tt * Dd;
    __shared__ float As[KST][TILE];
    __shared__ float Bs[KST][TILE];
    const int tid = threadIdx.x, tx = tid & 15, ty = tid >> 4;
    const int m0 = blockIdx.y * TILE, n0 = blockIdx.x * TILE;
    const int ar = tid >> 1, ac = (tid & 1) * 4;
    const int br = tid >> 5, bc = (tid & 31) * 4;
    float acc[8][8] = {};
    for (int k0 = 0; k0 < Ss; k0 += KST) {
        float4 av = *(const float4*)&A[(size_t)(m0 + ar) * Ss + k0 + ac];
        float4 bv = *(const float4*)&Bm[(size_t)(k0 + br) * Dd + n0 + bc];
        __syncthreads();
        As[ac + 0][ar] = av.x; As[ac + 1][ar] = av.y;
        As[ac + 2][ar] = av.z; As[ac + 3][ar] = av.w;
        *(float4*)&Bs[br][bc] = bv;
        __syncthreads();
#pragma unroll
        for (int k = 0; k < KST; ++k) {
            float a[8], b2[8];
            *(float4*)(a) = *(float4*)&As[k][ty * 8];
            *(float4*)(a + 4) = *(float4*)&As[k][ty * 8 + 4];
            *(float4*)(b2) = *(float4*)&Bs[k][tx * 8];
            *(float4*)(b2 + 4) = *(float4*)&Bs[k][tx * 8 + 4];
#pragma unroll
            for (int i = 0; i < 8; ++i)
#pragma unroll
                for (int j = 0; j < 8; ++j) acc[i][j] = fmaf(a[i], b2[j], acc[i][j]);
        }
    }
#pragma unroll
    for (int i = 0; i < 8; ++i) {
        float* cp = &C[(size_t)(m0 + ty * 8 + i) * Dd + n0 + tx * 8];
        *(float4*)(cp) = *(float4*)&acc[i][0];
        *(float4*)(cp + 4) = *(float4*)&acc[i][4];
    }
}

// ---------------------------------------------------------------------------
extern "C" void kernel_launch(void* const* d_in, const int* in_sizes, int n_in,
                              void* d_out, int out_size, void* d_ws, size_t ws_size,
                              hipStream_t stream) {
    const float* h_t = (const float*)d_in[0];   // [B,T,D]
    const float* h_s = (const float*)d_in[1];   // [B,S,D]
    const float* W_in = (const float*)d_in[2];  // [D,D]
    const int* m_s = (const int*)d_in[3];       // [B,S]

    float* ctx = (float*)d_out;                            // [B,T,D]
    float* scores = (float*)d_out + (size_t)Bb * Tt * Dd;  // [B,T,S]

    const size_t NHS = (size_t)Bb * Ss * Dd;  // 67,108,864 (== B*T*S = P elems)
    const size_t NHT = (size_t)Bb * Tt * Dd;  // 16,777,216
    const size_t NW = (size_t)Dd * Dd;        // 1,048,576
    // hs0 dead after gemm_scores -> p0 aliases it. No p1/hsT1 needed anymore.
    const size_t need = (3 * NHS + 4 * NHT + 2 * NW) * sizeof(_Float16);  // ~541 MB

    if (ws_size >= need) {
        _Float16* w = (_Float16*)d_ws;
        _Float16* hs0 = w;  w += NHS;   // reused as p0 after gemm_scores
        _Float16* hs1 = w;  w += NHS;
        _Float16* hsT0 = w; w += NHS;
        _Float16* ht0 = w;  w += NHT;
        _Float16* ht1 = w;  w += NHT;
        _Float16* wT0 = w;  w += NW;
        _Float16* wT1 = w;  w += NW;
        _Float16* q0 = w;   w += NHT;
        _Float16* q1 = w;   w += NHT;
        _Float16* p0 = hs0;             // overlay: hs split dead before softmax

        split2<<<(unsigned)(NHT / 8 / 256), 256, 0, stream>>>(h_t, ht0, ht1, NHT / 8);
        split2<<<(unsigned)(NHS / 8 / 256), 256, 0, stream>>>(h_s, hs0, hs1, NHS / 8);
        splitT<<<dim3(Dd / 32, Dd / 32, 1), 256, 0, stream>>>(W_in, wT0, wT1, Dd, Dd);
        splitT_hi<<<dim3(Dd / 32, Ss / 32, Bb), 256, 0, stream>>>(h_s, hsT0, Ss, Dd);

        // q = h_t @ W_in  (B-operand = W^T pre-transposed, both [row][k]) -> f16 split
        gemm_sp<Dd, 0><<<dim3(Dd / 128, (Bb * Tt) / 128, 1), 256, 0, stream>>>(
            ht0, ht1, wT0, wT1, nullptr, q0, q1, nullptr, 0, 0, 0);
        // scores = q @ h_s^T + mask/clamp   (last reader of hs0/hs1)
        gemm_sp<Dd, 1><<<dim3(Ss / 128, Tt / 128, Bb), 256, 0, stream>>>(
            q0, q1, hs0, hs1, scores, nullptr, nullptr, m_s,
            (size_t)Tt * Dd, (size_t)Ss * Dd, (size_t)Tt * Ss);
        // softmax + P-hi write (overwrites dead hs0; stream-ordered WAR)
        softmax_sp<<<Bb * Tt, 256, 0, stream>>>(scores, p0, 1);
        // ctx = P(hi) @ h_s(hi)  — 1 MFMA/k-chunk, hi-only operands
        gemm_hi<<<dim3(Dd / 128, Tt / 128, Bb), 256, 0, stream>>>(
            p0, hsT0, ctx, (size_t)Tt * Ss, (size_t)Dd * Ss, (size_t)Tt * Dd);
    } else {
        // fp32-vector fallback: only needs q scratch (67 MB)
        float* q = (float*)d_ws;
        fb_gemm_q<<<dim3(Dd / TILE, (Bb * Tt) / TILE), 256, 0, stream>>>(h_t, W_in, q);
        fb_gemm_scores<<<dim3(Ss / TILE, Tt / TILE, Bb), 256, 0, stream>>>(q, h_s, m_s, scores);
        softmax_sp<<<Bb * Tt, 256, 0, stream>>>(scores, nullptr, 0);
        fb_gemm_ctx<<<dim3(Dd / TILE, Tt / TILE, Bb), 256, 0, stream>>>(scores, h_s, ctx);
    }
}